// Round 1
// baseline (8335.764 us; speedup 1.0000x reference)
//
#include <hip/hip_runtime.h>
#include <math.h>

// Sizes (fixed for this problem)
// B=2, S=L=1024, h=16, k=128, d_c=512, d_cq=1536, r=64, dim_q=2048

// ---------------- rope tables: cos/sin [1024][64] ----------------
__global__ __launch_bounds__(64) void rope_tables_kernel(float* __restrict__ cosT,
                                                         float* __restrict__ sinT) {
  int s = blockIdx.x;
  int j = threadIdx.x;
  int i = j & 31;
  float inv = powf(10000.0f, -(float)(2 * i) / 64.0f);
  float ang = (float)s * inv;
  cosT[s * 64 + j] = cosf(ang);
  sinT[s * 64 + j] = sinf(ang);
}

// ---------------- fold1: tmp[h,k,r] = sum_q w_kc_q[h,k,q] * W_qr[h,q,r] ----------------
// grid (16, 32), block 256: 4 k-rows x 64 r per block
__global__ __launch_bounds__(256) void fold1_kernel(const float* __restrict__ w_kc_q,
                                                    const float* __restrict__ W_qr,
                                                    float* __restrict__ tmp) {
  int h = blockIdx.x;
  int k = blockIdx.y * 4 + (threadIdx.x >> 6);
  int r = threadIdx.x & 63;
  const float* wrow = w_kc_q + ((size_t)h * 128 + k) * 1536;
  const float* wq = W_qr + (size_t)h * 1536 * 64 + r;
  float acc = 0.f;
  for (int q = 0; q < 1536; ++q) acc = fmaf(wrow[q], wq[(size_t)q * 64], acc);
  tmp[((size_t)h * 128 + k) * 64 + r] = acc;
}

// ---------------- fold2: Wfold[d, h*64+r] = sum_k Wq[h*128+k, d] * tmp[h,k,r] ----------------
// grid (16, 32), block 256
__global__ __launch_bounds__(256) void fold2_kernel(const float* __restrict__ Wq,
                                                    const float* __restrict__ tmp,
                                                    float* __restrict__ Wfold) {
  int h = blockIdx.x;
  int d0 = blockIdx.y * 64;
  int dl = threadIdx.x >> 6;
  int r = threadIdx.x & 63;
  for (int i = 0; i < 16; ++i) {
    int d = d0 + i * 4 + dl;
    float acc = 0.f;
    for (int k = 0; k < 128; ++k)
      acc = fmaf(Wq[((size_t)h * 128 + k) * 2048 + d], tmp[((size_t)h * 128 + k) * 64 + r], acc);
    Wfold[(size_t)d * 1024 + h * 64 + r] = acc;
  }
}

// ---------------- proj: C[b,h,m%1024,r] = sum_d A[m,d] * Bw[h*sH + d*sD + r] ----------------
// grid (M/64, 16 heads), block 256, 4x4 micro-tile, BK=32
__global__ __launch_bounds__(256) void proj_kernel(const float* __restrict__ A,
                                                   const float* __restrict__ Bw,
                                                   float* __restrict__ Cq,
                                                   int Kdim, int sH, int sD) {
  __shared__ __align__(16) float As[64][33];
  __shared__ __align__(16) float Bs[32][64];
  int m0 = blockIdx.x * 64;
  int h = blockIdx.y;
  int tid = threadIdx.x;
  int ti = tid >> 4, tj = tid & 15;
  float acc[4][4] = {};
  for (int k0 = 0; k0 < Kdim; k0 += 32) {
    for (int e = tid; e < 64 * 32; e += 256) {
      int i = e >> 5, j = e & 31;
      As[i][j] = A[(size_t)(m0 + i) * Kdim + k0 + j];
    }
    for (int e = tid; e < 32 * 64; e += 256) {
      int j = e >> 6, r = e & 63;
      Bs[j][r] = Bw[(size_t)h * sH + (size_t)(k0 + j) * sD + r];
    }
    __syncthreads();
#pragma unroll
    for (int kk = 0; kk < 32; ++kk) {
      float av[4];
#pragma unroll
      for (int u = 0; u < 4; ++u) av[u] = As[ti * 4 + u][kk];
      float4 b = *(const float4*)&Bs[kk][tj * 4];
#pragma unroll
      for (int u = 0; u < 4; ++u) {
        acc[u][0] = fmaf(av[u], b.x, acc[u][0]);
        acc[u][1] = fmaf(av[u], b.y, acc[u][1]);
        acc[u][2] = fmaf(av[u], b.z, acc[u][2]);
        acc[u][3] = fmaf(av[u], b.w, acc[u][3]);
      }
    }
    __syncthreads();
  }
#pragma unroll
  for (int u = 0; u < 4; ++u) {
    int m = m0 + ti * 4 + u;
    int b = m >> 10, sl = m & 1023;
    float* cp = Cq + (((size_t)b * 16 + h) * 1024 + sl) * 64 + tj * 4;
    cp[0] = acc[u][0];
    cp[1] = acc[u][1];
    cp[2] = acc[u][2];
    cp[3] = acc[u][3];
  }
}

// ---------------- rope apply, in place over [B*H, 1024, 64] ----------------
__global__ __launch_bounds__(256) void rope_apply_kernel(float* __restrict__ X,
                                                         const float* __restrict__ cosT,
                                                         const float* __restrict__ sinT) {
  int gid = blockIdx.x * 256 + threadIdx.x;
  int j = gid & 63;
  int pos = (gid >> 6) & 1023;
  float x = X[gid];
  float other = __shfl_xor(x, 32);
  float rot = (j < 32) ? -other : other;
  X[gid] = fmaf(x, cosT[pos * 64 + j], rot * sinT[pos * 64 + j]);
}

// ---------------- fused flash attention: ctx[b,h,s,d] ----------------
// grid (B*h=32, S/32=32), block 256 (4 waves). Each thread: row sl=tid>>3, d-slice t=tid&7 (64 d vals).
__global__ __launch_bounds__(256) void flash_kernel(const float* __restrict__ qr,
                                                    const float* __restrict__ kr,
                                                    const float* __restrict__ kvc,
                                                    float* __restrict__ ctx) {
  __shared__ __align__(16) float Qs[32][64];
  __shared__ __align__(16) float Ks[64][68];
  __shared__ float Ps[32][72];
  __shared__ float ms[32], ls[32];
  int bh = blockIdx.x;
  int b = bh >> 4;
  int s0 = blockIdx.y * 32;
  int tid = threadIdx.x;
  int sl = tid >> 3;
  int t = tid & 7;
  const float* qbase = qr + ((size_t)bh * 1024 + s0) * 64;
  for (int e = tid; e < 32 * 64; e += 256) Qs[e >> 6][e & 63] = qbase[e];
  if (tid < 32) {
    ms[tid] = -INFINITY;
    ls[tid] = 0.f;
  }
  float4 acc[16];
#pragma unroll
  for (int i = 0; i < 16; ++i) acc[i] = make_float4(0.f, 0.f, 0.f, 0.f);
  const float* kvb = kvc + (size_t)b * 1024 * 512;
  const float* krb = kr + (size_t)bh * 1024 * 64;
  for (int l0 = 0; l0 < 1024; l0 += 64) {
    __syncthreads();  // protect Ks/Ps from previous iteration readers
    for (int e = tid; e < 64 * 64; e += 256) Ks[e >> 6][e & 63] = krb[(size_t)l0 * 64 + e];
    __syncthreads();
    // scores for 8 l-columns (l = li*8 + t) of row sl
    float sc[8] = {0, 0, 0, 0, 0, 0, 0, 0};
#pragma unroll
    for (int j4 = 0; j4 < 16; ++j4) {
      float4 q4 = *(const float4*)&Qs[sl][j4 * 4];
#pragma unroll
      for (int li = 0; li < 8; ++li) {
        float4 k4 = *(const float4*)&Ks[li * 8 + t][j4 * 4];
        sc[li] = fmaf(q4.x, k4.x, fmaf(q4.y, k4.y, fmaf(q4.z, k4.z, fmaf(q4.w, k4.w, sc[li]))));
      }
    }
    float tmax = sc[0];
#pragma unroll
    for (int li = 1; li < 8; ++li) tmax = fmaxf(tmax, sc[li]);
    tmax = fmaxf(tmax, __shfl_xor(tmax, 1));
    tmax = fmaxf(tmax, __shfl_xor(tmax, 2));
    tmax = fmaxf(tmax, __shfl_xor(tmax, 4));
    float oldm = ms[sl];
    float newm = fmaxf(oldm, tmax);
    float p[8];
    float psum = 0.f;
#pragma unroll
    for (int li = 0; li < 8; ++li) {
      p[li] = __expf(sc[li] - newm);
      psum += p[li];
    }
    psum += __shfl_xor(psum, 1);
    psum += __shfl_xor(psum, 2);
    psum += __shfl_xor(psum, 4);
    float scale = __expf(oldm - newm);
    if (t == 0) {
      ls[sl] = ls[sl] * scale + psum;
      ms[sl] = newm;
    }
#pragma unroll
    for (int li = 0; li < 8; ++li) Ps[sl][li * 8 + t] = p[li];
    __syncthreads();
    // PV: rescale acc, accumulate p * kv
#pragma unroll
    for (int i = 0; i < 16; ++i) {
      acc[i].x *= scale;
      acc[i].y *= scale;
      acc[i].z *= scale;
      acc[i].w *= scale;
    }
    for (int l = 0; l < 64; ++l) {
      float pv = Ps[sl][l];
      const float4* kv4 = (const float4*)(kvb + (size_t)(l0 + l) * 512 + t * 64);
#pragma unroll
      for (int i = 0; i < 16; ++i) {
        float4 v = kv4[i];
        acc[i].x = fmaf(pv, v.x, acc[i].x);
        acc[i].y = fmaf(pv, v.y, acc[i].y);
        acc[i].z = fmaf(pv, v.z, acc[i].z);
        acc[i].w = fmaf(pv, v.w, acc[i].w);
      }
    }
  }
  __syncthreads();
  float invl = 1.0f / ls[sl];
  float* outp = ctx + ((size_t)bh * 1024 + s0 + sl) * 512 + t * 64;
#pragma unroll
  for (int i = 0; i < 16; ++i) {
    float4 v = acc[i];
    v.x *= invl;
    v.y *= invl;
    v.z *= invl;
    v.w *= invl;
    ((float4*)outp)[i] = v;
  }
}

// ---------------- generic C = A @ B^T tile GEMM (batched via grid.z) ----------------
// grid (M/64, N/64, Z), block 256, 4x4 micro-tile, BK=32
// aOff = z*aZ; bOff = (z&15)*bZ; cOff = (z>>4)*cZb + (z&15)*cZh
__global__ __launch_bounds__(256) void gemm_abt_kernel(const float* __restrict__ A,
                                                       const float* __restrict__ Bm,
                                                       float* __restrict__ C,
                                                       int Kdim, int lda, int ldb, int ldc,
                                                       int aZ, int bZ, int cZb, int cZh) {
  __shared__ __align__(16) float As[64][33];
  __shared__ __align__(16) float Bs[64][33];
  int z = blockIdx.z;
  const float* Ap = A + (size_t)z * aZ;
  const float* Bp = Bm + (size_t)(z & 15) * bZ;
  float* Cp = C + (size_t)(z >> 4) * cZb + (size_t)(z & 15) * cZh;
  int m0 = blockIdx.x * 64, n0 = blockIdx.y * 64;
  int tid = threadIdx.x;
  int ti = tid >> 4, tj = tid & 15;
  float acc[4][4] = {};
  for (int k0 = 0; k0 < Kdim; k0 += 32) {
    for (int e = tid; e < 64 * 32; e += 256) {
      int i = e >> 5, j = e & 31;
      As[i][j] = Ap[(size_t)(m0 + i) * lda + k0 + j];
      Bs[i][j] = Bp[(size_t)(n0 + i) * ldb + k0 + j];
    }
    __syncthreads();
#pragma unroll
    for (int kk = 0; kk < 32; ++kk) {
      float av[4], bv[4];
#pragma unroll
      for (int u = 0; u < 4; ++u) av[u] = As[ti * 4 + u][kk];
#pragma unroll
      for (int v = 0; v < 4; ++v) bv[v] = Bs[tj * 4 + v][kk];
#pragma unroll
      for (int u = 0; u < 4; ++u)
#pragma unroll
        for (int v = 0; v < 4; ++v) acc[u][v] = fmaf(av[u], bv[v], acc[u][v]);
    }
    __syncthreads();
  }
#pragma unroll
  for (int u = 0; u < 4; ++u)
#pragma unroll
    for (int v = 0; v < 4; ++v)
      Cp[(size_t)(m0 + ti * 4 + u) * ldc + n0 + tj * 4 + v] = acc[u][v];
}

extern "C" void kernel_launch(void* const* d_in, const int* in_sizes, int n_in,
                              void* d_out, int out_size, void* d_ws, size_t ws_size,
                              hipStream_t stream) {
  const float* hidden_q = (const float*)d_in[0];
  const float* kv_c = (const float*)d_in[1];
  const float* Wq = (const float*)d_in[2];
  const float* w_kc_q = (const float*)d_in[3];
  const float* W_qr = (const float*)d_in[4];
  const float* W_kr = (const float*)d_in[5];
  const float* w_kc_kv = (const float*)d_in[6];
  const float* Wo = (const float*)d_in[7];
  float* out = (float*)d_out;

  float* ws = (float*)d_ws;
  float* qr = ws;                    // 2,097,152 floats
  float* kr = qr + 2097152;          // 2,097,152
  float* cosT = kr + 2097152;        // 65,536
  float* sinT = cosT + 65536;        // 65,536
  float* ctx = sinT + 65536;         // 16,777,216
  float* ctxlat = ctx + 16777216;    // 4,194,304
  // fold temporaries overlaid on ctx region (dead before flash_kernel runs)
  float* tmp = ctx;                  // 131,072
  float* Wfold = ctx + 131072;       // 2,097,152

  rope_tables_kernel<<<dim3(1024), dim3(64), 0, stream>>>(cosT, sinT);
  fold1_kernel<<<dim3(16, 32), dim3(256), 0, stream>>>(w_kc_q, W_qr, tmp);
  fold2_kernel<<<dim3(16, 32), dim3(256), 0, stream>>>(Wq, tmp, Wfold);
  // q_r = hidden_q @ Wfold  (K=2048, Bel = Wfold[d*1024 + h*64 + r] -> sH=64, sD=1024)
  proj_kernel<<<dim3(32, 16), dim3(256), 0, stream>>>(hidden_q, Wfold, qr, 2048, 64, 1024);
  // k_r = kv_c @ W_kr[h]    (K=512, Bel = W_kr[h*32768 + d*64 + r])
  proj_kernel<<<dim3(32, 16), dim3(256), 0, stream>>>(kv_c, W_kr, kr, 512, 32768, 64);
  rope_apply_kernel<<<dim3(8192), dim3(256), 0, stream>>>(qr, cosT, sinT);
  rope_apply_kernel<<<dim3(8192), dim3(256), 0, stream>>>(kr, cosT, sinT);
  flash_kernel<<<dim3(32, 32), dim3(256), 0, stream>>>(qr, kr, kv_c, ctx);
  // ctx_lat[b,s,h*128+kk] = sum_d ctx[b,h,s,d] * w_kc_kv[h,kk,d]
  gemm_abt_kernel<<<dim3(16, 2, 32), dim3(256), 0, stream>>>(
      ctx, w_kc_kv, ctxlat, 512, 512, 512, 2048, 524288, 65536, 2097152, 128);
  // out = ctx_lat @ Wo^T
  gemm_abt_kernel<<<dim3(32, 32, 1), dim3(256), 0, stream>>>(
      ctxlat, Wo, out, 2048, 2048, 2048, 2048, 0, 0, 0, 0);
}

// Round 2
// 1402.356 us; speedup vs baseline: 5.9441x; 5.9441x over previous
//
#include <hip/hip_runtime.h>
#include <math.h>

// Sizes (fixed): B=2, S=L=1024, h=16, k=128, d_c=512, d_cq=1536, r=64, dim_q=2048

// ---------------- rope tables: cos/sin [1024][64] ----------------
__global__ __launch_bounds__(64) void rope_tables_kernel(float* __restrict__ cosT,
                                                         float* __restrict__ sinT) {
  int s = blockIdx.x;
  int j = threadIdx.x;
  int i = j & 31;
  float inv = powf(10000.0f, -(float)(2 * i) / 64.0f);
  float ang = (float)s * inv;
  cosT[s * 64 + j] = cosf(ang);
  sinT[s * 64 + j] = sinf(ang);
}

// ---------------- fold1: tmp[h,k,r] = sum_q w_kc_q[h,k,q] * W_qr[h,q,r] ----------------
__global__ __launch_bounds__(256) void fold1_kernel(const float* __restrict__ w_kc_q,
                                                    const float* __restrict__ W_qr,
                                                    float* __restrict__ tmp) {
  int h = blockIdx.x;
  int k = blockIdx.y * 4 + (threadIdx.x >> 6);
  int r = threadIdx.x & 63;
  const float* wrow = w_kc_q + ((size_t)h * 128 + k) * 1536;
  const float* wq = W_qr + (size_t)h * 1536 * 64 + r;
  float acc = 0.f;
  for (int q = 0; q < 1536; ++q) acc = fmaf(wrow[q], wq[(size_t)q * 64], acc);
  tmp[((size_t)h * 128 + k) * 64 + r] = acc;
}

// ---------------- fold2: Wfold[d, h*64+r] = sum_k Wq[h*128+k, d] * tmp[h,k,r] ----------------
__global__ __launch_bounds__(256) void fold2_kernel(const float* __restrict__ Wq,
                                                    const float* __restrict__ tmp,
                                                    float* __restrict__ Wfold) {
  int h = blockIdx.x;
  int d0 = blockIdx.y * 64;
  int dl = threadIdx.x >> 6;
  int r = threadIdx.x & 63;
  for (int i = 0; i < 16; ++i) {
    int d = d0 + i * 4 + dl;
    float acc = 0.f;
    for (int k = 0; k < 128; ++k)
      acc = fmaf(Wq[((size_t)h * 128 + k) * 2048 + d], tmp[((size_t)h * 128 + k) * 64 + r], acc);
    Wfold[(size_t)d * 1024 + h * 64 + r] = acc;
  }
}

// ---------------- proj: C[b,h,m%1024,r] = sum_d A[m,d] * Bw[h*sH + d*sD + r] ----------------
__global__ __launch_bounds__(256) void proj_kernel(const float* __restrict__ A,
                                                   const float* __restrict__ Bw,
                                                   float* __restrict__ Cq,
                                                   int Kdim, int sH, int sD) {
  __shared__ __align__(16) float As[64][33];
  __shared__ __align__(16) float Bs[32][64];
  int m0 = blockIdx.x * 64;
  int h = blockIdx.y;
  int tid = threadIdx.x;
  int ti = tid >> 4, tj = tid & 15;
  float acc[4][4] = {};
  for (int k0 = 0; k0 < Kdim; k0 += 32) {
    for (int e = tid; e < 64 * 32; e += 256) {
      int i = e >> 5, j = e & 31;
      As[i][j] = A[(size_t)(m0 + i) * Kdim + k0 + j];
    }
    for (int e = tid; e < 32 * 64; e += 256) {
      int j = e >> 6, r = e & 63;
      Bs[j][r] = Bw[(size_t)h * sH + (size_t)(k0 + j) * sD + r];
    }
    __syncthreads();
#pragma unroll
    for (int kk = 0; kk < 32; ++kk) {
      float av[4];
#pragma unroll
      for (int u = 0; u < 4; ++u) av[u] = As[ti * 4 + u][kk];
      float4 b = *(const float4*)&Bs[kk][tj * 4];
#pragma unroll
      for (int u = 0; u < 4; ++u) {
        acc[u][0] = fmaf(av[u], b.x, acc[u][0]);
        acc[u][1] = fmaf(av[u], b.y, acc[u][1]);
        acc[u][2] = fmaf(av[u], b.z, acc[u][2]);
        acc[u][3] = fmaf(av[u], b.w, acc[u][3]);
      }
    }
    __syncthreads();
  }
#pragma unroll
  for (int u = 0; u < 4; ++u) {
    int m = m0 + ti * 4 + u;
    int b = m >> 10, sl = m & 1023;
    float* cp = Cq + (((size_t)b * 16 + h) * 1024 + sl) * 64 + tj * 4;
    cp[0] = acc[u][0];
    cp[1] = acc[u][1];
    cp[2] = acc[u][2];
    cp[3] = acc[u][3];
  }
}

// ---------------- rope apply, in place over [B*H, 1024, 64] ----------------
__global__ __launch_bounds__(256) void rope_apply_kernel(float* __restrict__ X,
                                                         const float* __restrict__ cosT,
                                                         const float* __restrict__ sinT) {
  int gid = blockIdx.x * 256 + threadIdx.x;
  int j = gid & 63;
  int pos = (gid >> 6) & 1023;
  float x = X[gid];
  float other = __shfl_xor(x, 32);
  float rot = (j < 32) ? -other : other;
  X[gid] = fmaf(x, cosT[pos * 64 + j], rot * sinT[pos * 64 + j]);
}

// ---------------- V_h[b,h,l,kk] = sum_d kv_c[b,l,d] * w_kc_kv[h,kk,d] ----------------
// grid (32, 2, 16), block 256
__global__ __launch_bounds__(256) void vh_kernel(const float* __restrict__ kvc,
                                                 const float* __restrict__ wkckv,
                                                 float* __restrict__ Vh) {
  __shared__ __align__(16) float As[64][33];
  __shared__ __align__(16) float Bs[64][33];
  int h = blockIdx.z;
  int m0 = blockIdx.x * 64, n0 = blockIdx.y * 64;
  const float* Bp = wkckv + (size_t)h * 128 * 512;
  int tid = threadIdx.x;
  int ti = tid >> 4, tj = tid & 15;
  float acc[4][4] = {};
  for (int k0 = 0; k0 < 512; k0 += 32) {
    for (int e = tid; e < 64 * 32; e += 256) {
      int i = e >> 5, j = e & 31;
      As[i][j] = kvc[(size_t)(m0 + i) * 512 + k0 + j];
      Bs[i][j] = Bp[(size_t)(n0 + i) * 512 + k0 + j];
    }
    __syncthreads();
#pragma unroll
    for (int kk = 0; kk < 32; ++kk) {
      float av[4], bv[4];
#pragma unroll
      for (int u = 0; u < 4; ++u) av[u] = As[ti * 4 + u][kk];
#pragma unroll
      for (int v = 0; v < 4; ++v) bv[v] = Bs[tj * 4 + v][kk];
#pragma unroll
      for (int u = 0; u < 4; ++u)
#pragma unroll
        for (int v = 0; v < 4; ++v) acc[u][v] = fmaf(av[u], bv[v], acc[u][v]);
    }
    __syncthreads();
  }
#pragma unroll
  for (int u = 0; u < 4; ++u) {
    int m = m0 + ti * 4 + u;
    int b = m >> 10, l = m & 1023;
    float* cp = Vh + (((size_t)b * 16 + h) * 1024 + l) * 128 + n0 + tj * 4;
#pragma unroll
    for (int v = 0; v < 4; ++v) cp[v] = acc[u][v];
  }
}

// ---------------- fused flash attention over absorbed values ----------------
// out: ctx_lat[b, s, h*128+kk]. grid (B*h=32, S/32=32), block 256.
__global__ __launch_bounds__(256, 2) void flash2_kernel(const float* __restrict__ qr,
                                                        const float* __restrict__ kr,
                                                        const float* __restrict__ Vh,
                                                        float* __restrict__ ctxlat) {
  __shared__ __align__(16) float Ks[64][68];
  __shared__ __align__(16) float Vs[64][128];
  __shared__ __align__(16) float Ps[32][72];
  __shared__ float ms[32], ls[32], rowscale[32];
  int bh = blockIdx.x;
  int b = bh >> 4, h = bh & 15;
  int s0 = blockIdx.y * 32;
  int tid = threadIdx.x;
  int sl = tid >> 3, t = tid & 7;     // QK mapping: row sl, cols li*8+t
  int rg = tid >> 5, kk4 = tid & 31;  // PV mapping: rows rg*4..+3, float4 col kk4

  // hoist this thread's q row into registers (row s0+sl, 64 floats)
  const float* qrow = qr + ((size_t)bh * 1024 + s0 + sl) * 64;
  float4 qreg[16];
#pragma unroll
  for (int j4 = 0; j4 < 16; ++j4) qreg[j4] = ((const float4*)qrow)[j4];

  if (tid < 32) {
    ms[tid] = -INFINITY;
    ls[tid] = 0.f;
  }
  float4 acc4[4];
#pragma unroll
  for (int u = 0; u < 4; ++u) acc4[u] = make_float4(0.f, 0.f, 0.f, 0.f);

  const float* krb = kr + (size_t)bh * 1024 * 64;
  const float* vhb = Vh + (size_t)bh * 1024 * 128;

  for (int l0 = 0; l0 < 1024; l0 += 64) {
    __syncthreads();  // previous iteration done reading Ks/Vs/Ps
    for (int e = tid; e < 64 * 64; e += 256) Ks[e >> 6][e & 63] = krb[(size_t)l0 * 64 + e];
    for (int e = tid; e < 64 * 128; e += 256) Vs[e >> 7][e & 127] = vhb[(size_t)l0 * 128 + e];
    __syncthreads();

    // QK^T: 8 scores per thread (cols l = li*8 + t)
    float sc8[8] = {0, 0, 0, 0, 0, 0, 0, 0};
#pragma unroll
    for (int j4 = 0; j4 < 16; ++j4) {
      float4 q4 = qreg[j4];
#pragma unroll
      for (int li = 0; li < 8; ++li) {
        float4 k4 = *(const float4*)&Ks[li * 8 + t][j4 * 4];
        sc8[li] = fmaf(q4.x, k4.x, fmaf(q4.y, k4.y, fmaf(q4.z, k4.z, fmaf(q4.w, k4.w, sc8[li]))));
      }
    }
    float tmax = sc8[0];
#pragma unroll
    for (int li = 1; li < 8; ++li) tmax = fmaxf(tmax, sc8[li]);
    tmax = fmaxf(tmax, __shfl_xor(tmax, 1));
    tmax = fmaxf(tmax, __shfl_xor(tmax, 2));
    tmax = fmaxf(tmax, __shfl_xor(tmax, 4));
    float oldm = ms[sl];
    float newm = fmaxf(oldm, tmax);
    float p8[8], psum = 0.f;
#pragma unroll
    for (int li = 0; li < 8; ++li) {
      p8[li] = __expf(sc8[li] - newm);
      psum += p8[li];
    }
    psum += __shfl_xor(psum, 1);
    psum += __shfl_xor(psum, 2);
    psum += __shfl_xor(psum, 4);
    float scale = __expf(oldm - newm);
    if (t == 0) {
      ls[sl] = ls[sl] * scale + psum;
      ms[sl] = newm;
      rowscale[sl] = scale;
    }
#pragma unroll
    for (int li = 0; li < 8; ++li) Ps[sl][li * 8 + t] = p8[li];
    __syncthreads();

    // PV: acc[rows rg*4..+3][kk4*4..+3] += P * Vs
#pragma unroll
    for (int u = 0; u < 4; ++u) {
      float rs = rowscale[rg * 4 + u];
      acc4[u].x *= rs;
      acc4[u].y *= rs;
      acc4[u].z *= rs;
      acc4[u].w *= rs;
    }
#pragma unroll 4
    for (int l4 = 0; l4 < 16; ++l4) {
      float4 pr[4];
#pragma unroll
      for (int u = 0; u < 4; ++u) pr[u] = *(const float4*)&Ps[rg * 4 + u][l4 * 4];
#pragma unroll
      for (int j = 0; j < 4; ++j) {
        float4 v = *(const float4*)&Vs[l4 * 4 + j][kk4 * 4];
#pragma unroll
        for (int u = 0; u < 4; ++u) {
          float pu = ((const float*)&pr[u])[j];
          acc4[u].x = fmaf(pu, v.x, acc4[u].x);
          acc4[u].y = fmaf(pu, v.y, acc4[u].y);
          acc4[u].z = fmaf(pu, v.z, acc4[u].z);
          acc4[u].w = fmaf(pu, v.w, acc4[u].w);
        }
      }
    }
  }
  // epilogue: normalize and store (ls/rowscale visible from last pre-PV barrier)
#pragma unroll
  for (int u = 0; u < 4; ++u) {
    float invl = 1.0f / ls[rg * 4 + u];
    float4 v = acc4[u];
    v.x *= invl;
    v.y *= invl;
    v.z *= invl;
    v.w *= invl;
    float* outp = ctxlat + ((size_t)(b * 1024 + s0 + rg * 4 + u)) * 2048 + h * 128 + kk4 * 4;
    *(float4*)outp = v;
  }
}

// ---------------- generic C = A @ B^T tile GEMM ----------------
__global__ __launch_bounds__(256) void gemm_abt_kernel(const float* __restrict__ A,
                                                       const float* __restrict__ Bm,
                                                       float* __restrict__ C,
                                                       int Kdim, int lda, int ldb, int ldc) {
  __shared__ __align__(16) float As[64][33];
  __shared__ __align__(16) float Bs[64][33];
  int m0 = blockIdx.x * 64, n0 = blockIdx.y * 64;
  int tid = threadIdx.x;
  int ti = tid >> 4, tj = tid & 15;
  float acc[4][4] = {};
  for (int k0 = 0; k0 < Kdim; k0 += 32) {
    for (int e = tid; e < 64 * 32; e += 256) {
      int i = e >> 5, j = e & 31;
      As[i][j] = A[(size_t)(m0 + i) * lda + k0 + j];
      Bs[i][j] = Bm[(size_t)(n0 + i) * ldb + k0 + j];
    }
    __syncthreads();
#pragma unroll
    for (int kk = 0; kk < 32; ++kk) {
      float av[4], bv[4];
#pragma unroll
      for (int u = 0; u < 4; ++u) av[u] = As[ti * 4 + u][kk];
#pragma unroll
      for (int v = 0; v < 4; ++v) bv[v] = Bs[tj * 4 + v][kk];
#pragma unroll
      for (int u = 0; u < 4; ++u)
#pragma unroll
        for (int v = 0; v < 4; ++v) acc[u][v] = fmaf(av[u], bv[v], acc[u][v]);
    }
    __syncthreads();
  }
#pragma unroll
  for (int u = 0; u < 4; ++u)
#pragma unroll
    for (int v = 0; v < 4; ++v)
      C[(size_t)(m0 + ti * 4 + u) * ldc + n0 + tj * 4 + v] = acc[u][v];
}

extern "C" void kernel_launch(void* const* d_in, const int* in_sizes, int n_in,
                              void* d_out, int out_size, void* d_ws, size_t ws_size,
                              hipStream_t stream) {
  const float* hidden_q = (const float*)d_in[0];
  const float* kv_c = (const float*)d_in[1];
  const float* Wq = (const float*)d_in[2];
  const float* w_kc_q = (const float*)d_in[3];
  const float* W_qr = (const float*)d_in[4];
  const float* W_kr = (const float*)d_in[5];
  const float* w_kc_kv = (const float*)d_in[6];
  const float* Wo = (const float*)d_in[7];
  float* out = (float*)d_out;

  float* ws = (float*)d_ws;
  float* qr = ws;                  // 2,097,152 floats
  float* kr = qr + 2097152;        // 2,097,152
  float* cosT = kr + 2097152;      // 65,536
  float* sinT = cosT + 65536;      // 65,536
  float* Vh = sinT + 65536;        // 4,194,304  [B,h,1024,128]
  float* ctxlat = Vh + 4194304;    // 4,194,304  [B,S,2048]
  // fold temporaries overlaid on ctxlat (dead before flash2 writes it)
  float* tmp = ctxlat;             // 131,072
  float* Wfold = ctxlat + 131072;  // 2,097,152

  rope_tables_kernel<<<dim3(1024), dim3(64), 0, stream>>>(cosT, sinT);
  fold1_kernel<<<dim3(16, 32), dim3(256), 0, stream>>>(w_kc_q, W_qr, tmp);
  fold2_kernel<<<dim3(16, 32), dim3(256), 0, stream>>>(Wq, tmp, Wfold);
  proj_kernel<<<dim3(32, 16), dim3(256), 0, stream>>>(hidden_q, Wfold, qr, 2048, 64, 1024);
  proj_kernel<<<dim3(32, 16), dim3(256), 0, stream>>>(kv_c, W_kr, kr, 512, 32768, 64);
  rope_apply_kernel<<<dim3(8192), dim3(256), 0, stream>>>(qr, cosT, sinT);
  rope_apply_kernel<<<dim3(8192), dim3(256), 0, stream>>>(kr, cosT, sinT);
  vh_kernel<<<dim3(32, 2, 16), dim3(256), 0, stream>>>(kv_c, w_kc_kv, Vh);
  flash2_kernel<<<dim3(32, 32), dim3(256), 0, stream>>>(qr, kr, Vh, ctxlat);
  gemm_abt_kernel<<<dim3(32, 32), dim3(256), 0, stream>>>(ctxlat, Wo, out, 2048, 2048, 2048, 2048);
}

// Round 3
// 305.330 us; speedup vs baseline: 27.3008x; 4.5929x over previous
//
#include <hip/hip_runtime.h>
#include <math.h>
#include <stdint.h>

// Sizes (fixed): B=2, S=L=1024, h=16, k=128, d_c=512, d_cq=1536, r=64, dim_q=2048

typedef __attribute__((ext_vector_type(8))) short short8;
typedef __attribute__((ext_vector_type(4))) float f32x4;

#define GLOAD16(gsrc, ldst)                                                            \
  __builtin_amdgcn_global_load_lds((const __attribute__((address_space(1))) void*)(gsrc), \
                                   (__attribute__((address_space(3))) void*)(ldst), 16, 0, 0)

__device__ inline uint16_t f2b(float x) {  // round-to-nearest-even f32 -> bf16
  uint32_t u = __builtin_bit_cast(uint32_t, x);
  u += 0x7fff + ((u >> 16) & 1);
  return (uint16_t)(u >> 16);
}
__device__ inline float b2f(uint16_t b) {
  uint32_t u = ((uint32_t)b) << 16;
  return __builtin_bit_cast(float, u);
}

// ---------------- elementwise f32 -> bf16 convert (8 el/thread) ----------------
__global__ __launch_bounds__(256) void convert_kernel(const float* __restrict__ src,
                                                      uint16_t* __restrict__ dst) {
  int i = blockIdx.x * 256 + threadIdx.x;
  const float4* s4 = (const float4*)src;
  float4 a = s4[i * 2], b = s4[i * 2 + 1];
  union {
    uint16_t u[8];
    uint4 v;
  } o;
  o.u[0] = f2b(a.x); o.u[1] = f2b(a.y); o.u[2] = f2b(a.z); o.u[3] = f2b(a.w);
  o.u[4] = f2b(b.x); o.u[5] = f2b(b.y); o.u[6] = f2b(b.z); o.u[7] = f2b(b.w);
  ((uint4*)dst)[i] = o.v;
}

// ---------------- tiled transpose + convert: src f32 [R][C] -> dst bf16 [C][R] ----------------
__global__ __launch_bounds__(256) void transpose_conv_kernel(const float* __restrict__ src,
                                                             uint16_t* __restrict__ dst,
                                                             int R, int C, int sOff, int dOff) {
  __shared__ float t[32][33];
  src += (size_t)blockIdx.z * sOff;
  dst += (size_t)blockIdx.z * dOff;
  int r0 = blockIdx.x * 32, c0 = blockIdx.y * 32;
  int tr = threadIdx.x >> 5, tc = threadIdx.x & 31;
#pragma unroll
  for (int i = 0; i < 4; ++i) t[tr + i * 8][tc] = src[(size_t)(r0 + tr + i * 8) * C + c0 + tc];
  __syncthreads();
#pragma unroll
  for (int i = 0; i < 4; ++i)
    dst[(size_t)(c0 + tr + i * 8) * R + r0 + tc] = f2b(t[tc][tr + i * 8]);
}

// ---------------- rope tables: cos/sin [1024][64] ----------------
__global__ __launch_bounds__(64) void rope_tables_kernel(float* __restrict__ cosT,
                                                         float* __restrict__ sinT) {
  int s = blockIdx.x;
  int j = threadIdx.x;
  int i = j & 31;
  float inv = powf(10000.0f, -(float)(2 * i) / 64.0f);
  float ang = (float)s * inv;
  cosT[s * 64 + j] = cosf(ang);
  sinT[s * 64 + j] = sinf(ang);
}

// ---------------- fold1: tmp[h,k,r] = sum_q w_kc_q[h,k,q] * W_qr[h,q,r] ----------------
__global__ __launch_bounds__(256) void fold1_kernel(const float* __restrict__ w_kc_q,
                                                    const float* __restrict__ W_qr,
                                                    float* __restrict__ tmp) {
  int h = blockIdx.x;
  int k = blockIdx.y * 4 + (threadIdx.x >> 6);
  int r = threadIdx.x & 63;
  const float* wrow = w_kc_q + ((size_t)h * 128 + k) * 1536;
  const float* wq = W_qr + (size_t)h * 1536 * 64 + r;
  float acc = 0.f;
  for (int q = 0; q < 1536; ++q) acc = fmaf(wrow[q], wq[(size_t)q * 64], acc);
  tmp[((size_t)h * 128 + k) * 64 + r] = acc;
}

// ---------------- fold2: Wfold[d, h*64+r] = sum_k Wq[h*128+k, d] * tmp[h,k,r] ----------------
__global__ __launch_bounds__(256) void fold2_kernel(const float* __restrict__ Wq,
                                                    const float* __restrict__ tmp,
                                                    float* __restrict__ Wfold) {
  int h = blockIdx.x;
  int d0 = blockIdx.y * 64;
  int dl = threadIdx.x >> 6;
  int r = threadIdx.x & 63;
  for (int i = 0; i < 16; ++i) {
    int d = d0 + i * 4 + dl;
    float acc = 0.f;
    for (int k = 0; k < 128; ++k)
      acc = fmaf(Wq[((size_t)h * 128 + k) * 2048 + d], tmp[((size_t)h * 128 + k) * 64 + r], acc);
    Wfold[(size_t)d * 1024 + h * 64 + r] = acc;
  }
}

// ---------------- MFMA GEMM: C[M,N] = A[M,K]bf16 @ Bt[N,K]bf16^T ----------------
// 128x128 tile, BK=64, 256 thr (4 waves, 2x2), single-buffered LDS, XOR slot swizzle.
// EPI 0: f32 row-major; EPI 1: bf16 row-major; EPI 2: bf16 VhT layout ((m>>10)*2048+n)*1024+(m&1023)
template <int EPI>
__global__ __launch_bounds__(256) void gemm_mfma_kernel(const uint16_t* __restrict__ A,
                                                        const uint16_t* __restrict__ Bt,
                                                        void* __restrict__ Cv, int K, int N) {
  __shared__ __align__(16) uint16_t As[128 * 64];
  __shared__ __align__(16) uint16_t Bs[128 * 64];
  int m0 = blockIdx.x * 128, n0 = blockIdx.y * 128;
  int tid = threadIdx.x;
  int wave = tid >> 6, lane = tid & 63;
  int wm = wave >> 1, wn = wave & 1;
  int rS = lane >> 3, sl = lane & 7;  // staging: 8 rows x 8 slots per wave-instr
  int lr = lane >> 4, lc = lane & 15;
  f32x4 acc[4][4] = {};
  for (int k0 = 0; k0 < K; k0 += 64) {
    __syncthreads();
#pragma unroll
    for (int i = 0; i < 4; ++i) {
      int idx = wave * 4 + i;
      int row = idx * 8 + rS;
      int kel = k0 + ((sl ^ (row & 7)) << 3);
      GLOAD16(A + (size_t)(m0 + row) * K + kel, (uint8_t*)As + idx * 1024);
      GLOAD16(Bt + (size_t)(n0 + row) * K + kel, (uint8_t*)Bs + idx * 1024);
    }
    __syncthreads();
    short8 af[4][2], bf[4][2];
#pragma unroll
    for (int t = 0; t < 4; ++t) {
#pragma unroll
      for (int ks = 0; ks < 2; ++ks) {
        int slot = ks * 4 + lr;
        int ra = wm * 64 + t * 16 + lc;
        af[t][ks] = *(const short8*)((const uint8_t*)As + ra * 128 + (((slot ^ (ra & 7))) << 4));
        int rb = wn * 64 + t * 16 + lc;
        bf[t][ks] = *(const short8*)((const uint8_t*)Bs + rb * 128 + (((slot ^ (rb & 7))) << 4));
      }
    }
#pragma unroll
    for (int mt = 0; mt < 4; ++mt)
#pragma unroll
      for (int nt = 0; nt < 4; ++nt) {
        acc[mt][nt] =
            __builtin_amdgcn_mfma_f32_16x16x32_bf16(af[mt][0], bf[nt][0], acc[mt][nt], 0, 0, 0);
        acc[mt][nt] =
            __builtin_amdgcn_mfma_f32_16x16x32_bf16(af[mt][1], bf[nt][1], acc[mt][nt], 0, 0, 0);
      }
  }
#pragma unroll
  for (int mt = 0; mt < 4; ++mt)
#pragma unroll
    for (int nt = 0; nt < 4; ++nt)
#pragma unroll
      for (int r = 0; r < 4; ++r) {
        int m = m0 + wm * 64 + mt * 16 + lr * 4 + r;
        int n = n0 + wn * 64 + nt * 16 + lc;
        float v = acc[mt][nt][r];
        if (EPI == 0)
          ((float*)Cv)[(size_t)m * N + n] = v;
        else if (EPI == 1)
          ((uint16_t*)Cv)[(size_t)m * N + n] = f2b(v);
        else
          ((uint16_t*)Cv)[((size_t)((m >> 10) * 2048 + n)) * 1024 + (m & 1023)] = f2b(v);
      }
}

// ---------------- rope apply in place on bf16 [2048 rows][1024 cols] (col = h*64+r) -------------
__global__ __launch_bounds__(256) void rope_bf16_kernel(uint16_t* __restrict__ X,
                                                        const float* __restrict__ cosT,
                                                        const float* __restrict__ sinT) {
  int gid = blockIdx.x * 256 + threadIdx.x;
  int j = gid & 63;           // r
  int pos = (gid >> 10) & 1023;  // s (or l)
  float x = b2f(X[gid]);
  float other = __shfl_xor(x, 32);
  float rot = (j < 32) ? -other : other;
  X[gid] = f2b(fmaf(x, cosT[pos * 64 + j], rot * sinT[pos * 64 + j]));
}

// ---------------- MFMA flash attention ----------------
// grid (bh=32, stile=16), 256 thr = 4 waves; wave owns 16 q-rows. Out: ctxlatb bf16 [b*1024+s][2048]
__global__ __launch_bounds__(256) void flash3_kernel(const uint16_t* __restrict__ qrb,
                                                     const uint16_t* __restrict__ krb,
                                                     const uint16_t* __restrict__ VhT,
                                                     uint16_t* __restrict__ ctxlatb) {
  __shared__ __align__(16) uint16_t Ks[64 * 64];    // rows l, 64 r (128B, swizzled)
  __shared__ __align__(16) uint16_t Vs[128 * 64];   // rows kk, 64 l (128B, swizzled)
  __shared__ __align__(16) uint16_t Ps[4][16 * 64]; // per-wave P, swizzled
  int bh = blockIdx.x;
  int b = bh >> 4, h = bh & 15;
  int s0 = blockIdx.y * 64;
  int tid = threadIdx.x, wave = tid >> 6, lane = tid & 63;
  int lr = lane >> 4, lc = lane & 15;
  int rS = lane >> 3, sl = lane & 7;

  // Q fragments (A-operand): row = s0 + wave*16 + lc, k = ks*32 + lr*8
  const uint16_t* qrow = qrb + (size_t)(b * 1024 + s0 + wave * 16 + lc) * 1024 + h * 64;
  short8 qa[2];
  qa[0] = *(const short8*)(qrow + lr * 8);
  qa[1] = *(const short8*)(qrow + 32 + lr * 8);

  float m_run[4], l_run[4];
#pragma unroll
  for (int r = 0; r < 4; ++r) {
    m_run[r] = -1e30f;
    l_run[r] = 0.f;
  }
  f32x4 o[8] = {};

  const uint16_t* krbase = krb + (size_t)(b * 1024) * 1024 + h * 64;
  const uint16_t* vtbase = VhT + (size_t)(b * 2048 + h * 128) * 1024;

  for (int l0 = 0; l0 < 1024; l0 += 64) {
    __syncthreads();
#pragma unroll
    for (int i = 0; i < 2; ++i) {  // stage K tile: 8KB
      int idx = wave * 2 + i;
      int row = idx * 8 + rS;
      GLOAD16(krbase + (size_t)(l0 + row) * 1024 + ((sl ^ (row & 7)) << 3),
              (uint8_t*)Ks + idx * 1024);
    }
#pragma unroll
    for (int i = 0; i < 4; ++i) {  // stage V^T tile: 16KB
      int idx = wave * 4 + i;
      int row = idx * 8 + rS;
      GLOAD16(vtbase + (size_t)row * 1024 + l0 + ((sl ^ (row & 7)) << 3),
              (uint8_t*)Vs + idx * 1024);
    }
    __syncthreads();

    // QK^T: sc[nt] covers cols nt*16+lc, rows lr*4+r
    f32x4 sc[4];
#pragma unroll
    for (int nt = 0; nt < 4; ++nt) {
      int rowk = nt * 16 + lc;
      short8 kb0 = *(const short8*)((const uint8_t*)Ks + rowk * 128 + ((lr ^ (rowk & 7)) << 4));
      short8 kb1 =
          *(const short8*)((const uint8_t*)Ks + rowk * 128 + (((4 + lr) ^ (rowk & 7)) << 4));
      f32x4 z = {};
      z = __builtin_amdgcn_mfma_f32_16x16x32_bf16(qa[0], kb0, z, 0, 0, 0);
      sc[nt] = __builtin_amdgcn_mfma_f32_16x16x32_bf16(qa[1], kb1, z, 0, 0, 0);
    }

    // online softmax (wave-parallel, rows lr*4+r)
    float scale[4], rmax[4];
#pragma unroll
    for (int r = 0; r < 4; ++r) {
      float mx = fmaxf(fmaxf(sc[0][r], sc[1][r]), fmaxf(sc[2][r], sc[3][r]));
      mx = fmaxf(mx, __shfl_xor(mx, 1));
      mx = fmaxf(mx, __shfl_xor(mx, 2));
      mx = fmaxf(mx, __shfl_xor(mx, 4));
      mx = fmaxf(mx, __shfl_xor(mx, 8));
      float mn = fmaxf(m_run[r], mx);
      scale[r] = __expf(m_run[r] - mn);
      m_run[r] = mn;
      rmax[r] = mn;
    }
    float ps[4] = {0.f, 0.f, 0.f, 0.f};
#pragma unroll
    for (int nt = 0; nt < 4; ++nt)
#pragma unroll
      for (int r = 0; r < 4; ++r) {
        float p = __expf(sc[nt][r] - rmax[r]);
        ps[r] += p;
        int prow = lr * 4 + r;
        int pcol = nt * 16 + lc;
        uint32_t addr = prow * 128 + ((((pcol >> 3) ^ (prow & 7))) << 4) + (pcol & 7) * 2;
        *(uint16_t*)((uint8_t*)Ps[wave] + addr) = f2b(p);
      }
#pragma unroll
    for (int r = 0; r < 4; ++r) {
      float s = ps[r];
      s += __shfl_xor(s, 1);
      s += __shfl_xor(s, 2);
      s += __shfl_xor(s, 4);
      s += __shfl_xor(s, 8);
      l_run[r] = l_run[r] * scale[r] + s;
    }
#pragma unroll
    for (int nt = 0; nt < 8; ++nt)
#pragma unroll
      for (int r = 0; r < 4; ++r) o[nt][r] *= scale[r];

    // P as A-fragment (wave-local LDS bounce; compiler inserts lgkmcnt)
    short8 pa[2];
#pragma unroll
    for (int ks = 0; ks < 2; ++ks) {
      int slot = ks * 4 + lr;
      pa[ks] = *(const short8*)((const uint8_t*)Ps[wave] + lc * 128 + ((slot ^ (lc & 7)) << 4));
    }
    // PV: o[nt] covers kk cols nt*16+lc
#pragma unroll
    for (int nt = 0; nt < 8; ++nt) {
      int rowv = nt * 16 + lc;
      short8 vb0 = *(const short8*)((const uint8_t*)Vs + rowv * 128 + ((lr ^ (rowv & 7)) << 4));
      short8 vb1 =
          *(const short8*)((const uint8_t*)Vs + rowv * 128 + (((4 + lr) ^ (rowv & 7)) << 4));
      o[nt] = __builtin_amdgcn_mfma_f32_16x16x32_bf16(pa[0], vb0, o[nt], 0, 0, 0);
      o[nt] = __builtin_amdgcn_mfma_f32_16x16x32_bf16(pa[1], vb1, o[nt], 0, 0, 0);
    }
  }
  // epilogue
  uint16_t* orow = ctxlatb + (size_t)(b * 1024 + s0 + wave * 16) * 2048 + h * 128;
#pragma unroll
  for (int nt = 0; nt < 8; ++nt)
#pragma unroll
    for (int r = 0; r < 4; ++r)
      orow[(size_t)(lr * 4 + r) * 2048 + nt * 16 + lc] = f2b(o[nt][r] / l_run[r]);
}

extern "C" void kernel_launch(void* const* d_in, const int* in_sizes, int n_in,
                              void* d_out, int out_size, void* d_ws, size_t ws_size,
                              hipStream_t stream) {
  const float* hidden_q = (const float*)d_in[0];
  const float* kv_c = (const float*)d_in[1];
  const float* Wq = (const float*)d_in[2];
  const float* w_kc_q = (const float*)d_in[3];
  const float* W_qr = (const float*)d_in[4];
  const float* W_kr = (const float*)d_in[5];
  const float* w_kc_kv = (const float*)d_in[6];
  const float* Wo = (const float*)d_in[7];
  float* out = (float*)d_out;

  uint8_t* p = (uint8_t*)d_ws;
  float* cosT = (float*)p;      p += 262144;
  float* sinT = (float*)p;      p += 262144;
  uint16_t* hqb = (uint16_t*)p; p += 8388608;   // hidden_q bf16 [2048][2048]
  uint16_t* kvb = (uint16_t*)p; p += 2097152;   // kv_c bf16 [2048][512]
  uint16_t* wkvb = (uint16_t*)p; p += 2097152;  // w_kc_kv bf16 [2048][512]
  uint16_t* Wob = (uint16_t*)p; p += 8388608;   // Wo bf16 [2048][2048]
  uint16_t* WfoldT = (uint16_t*)p; p += 4194304;  // [1024][2048]
  uint16_t* qrb = (uint16_t*)p; p += 4194304;   // [2048][1024]
  uint16_t* krb = (uint16_t*)p; p += 4194304;   // [2048][1024]
  uint16_t* VhT = (uint16_t*)p; p += 8388608;   // [b*2048 + h*128 + kk][1024]
  uint8_t* X = p;                                // 8388608: Wfold f32 -> WkrT -> ctxlatb
  float* tmp = (float*)VhT;                      // fold1 temp (dead before VhT write)
  float* Wfold = (float*)X;
  uint16_t* WkrT = (uint16_t*)X;
  uint16_t* ctxlatb = (uint16_t*)X;

  convert_kernel<<<dim3(2048), dim3(256), 0, stream>>>(hidden_q, hqb);
  convert_kernel<<<dim3(512), dim3(256), 0, stream>>>(kv_c, kvb);
  convert_kernel<<<dim3(512), dim3(256), 0, stream>>>(w_kc_kv, wkvb);
  convert_kernel<<<dim3(2048), dim3(256), 0, stream>>>(Wo, Wob);
  rope_tables_kernel<<<dim3(1024), dim3(64), 0, stream>>>(cosT, sinT);
  fold1_kernel<<<dim3(16, 32), dim3(256), 0, stream>>>(w_kc_q, W_qr, tmp);
  fold2_kernel<<<dim3(16, 32), dim3(256), 0, stream>>>(Wq, tmp, Wfold);
  transpose_conv_kernel<<<dim3(64, 32, 1), dim3(256), 0, stream>>>(Wfold, WfoldT, 2048, 1024, 0, 0);
  transpose_conv_kernel<<<dim3(16, 2, 16), dim3(256), 0, stream>>>((const float*)W_kr, WkrT, 512,
                                                                   64, 32768, 32768);
  gemm_mfma_kernel<1><<<dim3(16, 8), dim3(256), 0, stream>>>(hqb, WfoldT, qrb, 2048, 1024);
  gemm_mfma_kernel<1><<<dim3(16, 8), dim3(256), 0, stream>>>(kvb, WkrT, krb, 512, 1024);
  gemm_mfma_kernel<2><<<dim3(16, 16), dim3(256), 0, stream>>>(kvb, wkvb, VhT, 512, 2048);
  rope_bf16_kernel<<<dim3(8192), dim3(256), 0, stream>>>(qrb, cosT, sinT);
  rope_bf16_kernel<<<dim3(8192), dim3(256), 0, stream>>>(krb, cosT, sinT);
  flash3_kernel<<<dim3(32, 16), dim3(256), 0, stream>>>(qrb, krb, VhT, ctxlatb);
  gemm_mfma_kernel<0><<<dim3(16, 16), dim3(256), 0, stream>>>(ctxlatb, Wob, out, 2048, 2048);
}

// Round 4
// 214.032 us; speedup vs baseline: 38.9464x; 1.4266x over previous
//
#include <hip/hip_runtime.h>
#include <math.h>
#include <stdint.h>

// Sizes (fixed): B=2, S=L=1024, h=16, k=128, d_c=512, d_cq=1536, r=64, dim_q=2048

typedef __attribute__((ext_vector_type(8))) short short8;
typedef __attribute__((ext_vector_type(4))) float f32x4;

#define GLOAD16(gsrc, ldst)                                                            \
  __builtin_amdgcn_global_load_lds((const __attribute__((address_space(1))) void*)(gsrc), \
                                   (__attribute__((address_space(3))) void*)(ldst), 16, 0, 0)

__device__ inline uint16_t f2b(float x) {  // round-to-nearest-even f32 -> bf16
  uint32_t u = __builtin_bit_cast(uint32_t, x);
  u += 0x7fff + ((u >> 16) & 1);
  return (uint16_t)(u >> 16);
}
__device__ inline float b2f(uint16_t b) {
  uint32_t u = ((uint32_t)b) << 16;
  return __builtin_bit_cast(float, u);
}

// ---------------- elementwise f32 -> bf16 convert (8 el/thread) ----------------
__global__ __launch_bounds__(256) void convert_kernel(const float* __restrict__ src,
                                                      uint16_t* __restrict__ dst) {
  int i = blockIdx.x * 256 + threadIdx.x;
  const float4* s4 = (const float4*)src;
  float4 a = s4[i * 2], b = s4[i * 2 + 1];
  union {
    uint16_t u[8];
    uint4 v;
  } o;
  o.u[0] = f2b(a.x); o.u[1] = f2b(a.y); o.u[2] = f2b(a.z); o.u[3] = f2b(a.w);
  o.u[4] = f2b(b.x); o.u[5] = f2b(b.y); o.u[6] = f2b(b.z); o.u[7] = f2b(b.w);
  ((uint4*)dst)[i] = o.v;
}

// ---------------- tiled transpose + convert: src f32 [R][C] -> dst bf16 [C][R] ----------------
__global__ __launch_bounds__(256) void transpose_conv_kernel(const float* __restrict__ src,
                                                             uint16_t* __restrict__ dst,
                                                             int R, int C, int sOff, int dOff) {
  __shared__ float t[32][33];
  src += (size_t)blockIdx.z * sOff;
  dst += (size_t)blockIdx.z * dOff;
  int r0 = blockIdx.x * 32, c0 = blockIdx.y * 32;
  int tr = threadIdx.x >> 5, tc = threadIdx.x & 31;
#pragma unroll
  for (int i = 0; i < 4; ++i) t[tr + i * 8][tc] = src[(size_t)(r0 + tr + i * 8) * C + c0 + tc];
  __syncthreads();
#pragma unroll
  for (int i = 0; i < 4; ++i)
    dst[(size_t)(c0 + tr + i * 8) * R + r0 + tc] = f2b(t[tc][tr + i * 8]);
}

// ---------------- rope tables: cos/sin [1024][64] ----------------
__global__ __launch_bounds__(64) void rope_tables_kernel(float* __restrict__ cosT,
                                                         float* __restrict__ sinT) {
  int s = blockIdx.x;
  int j = threadIdx.x;
  int i = j & 31;
  float inv = powf(10000.0f, -(float)(2 * i) / 64.0f);
  float ang = (float)s * inv;
  cosT[s * 64 + j] = cosf(ang);
  sinT[s * 64 + j] = sinf(ang);
}

// ---------------- MFMA GEMM: C[.., M, N] = A[z][M,K]bf16 @ Bt[z][N,K]bf16^T ----------------
// Tile BM x 128, BK=64, 256 thr (4 waves 2x2), XOR slot swizzle, global_load_lds staging.
// EPI 0: f32 row-major; EPI 1: bf16 row-major; EPI 2: bf16 VhT layout ((m>>10)*2048+n)*1024+(m&1023)
template <int BM, int EPI>
__global__ __launch_bounds__(256) void gemm_mfma_kernel(const uint16_t* __restrict__ A,
                                                        const uint16_t* __restrict__ Bt,
                                                        void* __restrict__ Cv, int K, int lda,
                                                        int ldb, int ldc, int aZ, int bZ,
                                                        int cZ) {
  constexpr int MT = BM / 32;  // m-fragments per wave (2 or 4)
  __shared__ __align__(16) uint16_t As[BM * 64];
  __shared__ __align__(16) uint16_t Bs[128 * 64];
  int z = blockIdx.z;
  A += (size_t)z * aZ;
  Bt += (size_t)z * bZ;
  int m0 = blockIdx.x * BM, n0 = blockIdx.y * 128;
  int tid = threadIdx.x;
  int wave = tid >> 6, lane = tid & 63;
  int wm = wave >> 1, wn = wave & 1;
  int rS = lane >> 3, sl = lane & 7;  // staging: 8 rows x 8 slots per wave-instr
  int lr = lane >> 4, lc = lane & 15;
  f32x4 acc[MT][4] = {};
  for (int k0 = 0; k0 < K; k0 += 64) {
    __syncthreads();
#pragma unroll
    for (int i = 0; i < MT; ++i) {
      int idx = wave * MT + i;
      int row = idx * 8 + rS;
      GLOAD16(A + (size_t)(m0 + row) * lda + k0 + ((sl ^ (row & 7)) << 3),
              (uint8_t*)As + idx * 1024);
    }
#pragma unroll
    for (int i = 0; i < 4; ++i) {
      int idx = wave * 4 + i;
      int row = idx * 8 + rS;
      GLOAD16(Bt + (size_t)(n0 + row) * ldb + k0 + ((sl ^ (row & 7)) << 3),
              (uint8_t*)Bs + idx * 1024);
    }
    __syncthreads();
    short8 af[MT][2], bf[4][2];
#pragma unroll
    for (int t = 0; t < MT; ++t)
#pragma unroll
      for (int ks = 0; ks < 2; ++ks) {
        int slot = ks * 4 + lr;
        int ra = wm * (BM / 2) + t * 16 + lc;
        af[t][ks] = *(const short8*)((const uint8_t*)As + ra * 128 + ((slot ^ (ra & 7)) << 4));
      }
#pragma unroll
    for (int t = 0; t < 4; ++t)
#pragma unroll
      for (int ks = 0; ks < 2; ++ks) {
        int slot = ks * 4 + lr;
        int rb = wn * 64 + t * 16 + lc;
        bf[t][ks] = *(const short8*)((const uint8_t*)Bs + rb * 128 + ((slot ^ (rb & 7)) << 4));
      }
#pragma unroll
    for (int mt = 0; mt < MT; ++mt)
#pragma unroll
      for (int nt = 0; nt < 4; ++nt) {
        acc[mt][nt] =
            __builtin_amdgcn_mfma_f32_16x16x32_bf16(af[mt][0], bf[nt][0], acc[mt][nt], 0, 0, 0);
        acc[mt][nt] =
            __builtin_amdgcn_mfma_f32_16x16x32_bf16(af[mt][1], bf[nt][1], acc[mt][nt], 0, 0, 0);
      }
  }
#pragma unroll
  for (int mt = 0; mt < MT; ++mt)
#pragma unroll
    for (int nt = 0; nt < 4; ++nt)
#pragma unroll
      for (int r = 0; r < 4; ++r) {
        int m = m0 + wm * (BM / 2) + mt * 16 + lr * 4 + r;
        int n = n0 + wn * 64 + nt * 16 + lc;
        float v = acc[mt][nt][r];
        if (EPI == 0)
          ((float*)Cv)[(size_t)z * cZ + (size_t)m * ldc + n] = v;
        else if (EPI == 1)
          ((uint16_t*)Cv)[(size_t)z * cZ + (size_t)m * ldc + n] = f2b(v);
        else
          ((uint16_t*)Cv)[((size_t)((m >> 10) * 2048 + n)) * 1024 + (m & 1023)] = f2b(v);
      }
}

// ---------------- rope apply in place on bf16 [2048 rows][1024 cols] (col = h*64+r) -------------
__global__ __launch_bounds__(256) void rope_bf16_kernel(uint16_t* __restrict__ X,
                                                        const float* __restrict__ cosT,
                                                        const float* __restrict__ sinT) {
  int gid = blockIdx.x * 256 + threadIdx.x;
  int j = gid & 63;              // r
  int pos = (gid >> 10) & 1023;  // s (or l)
  float x = b2f(X[gid]);
  float other = __shfl_xor(x, 32);
  float rot = (j < 32) ? -other : other;
  X[gid] = f2b(fmaf(x, cosT[pos * 64 + j], rot * sinT[pos * 64 + j]));
}

// ---------------- MFMA flash attention ----------------
// grid (bh=32, stile=16), 256 thr = 4 waves; wave owns 16 q-rows. Out: ctxlatb bf16 [b*1024+s][2048]
__global__ __launch_bounds__(256) void flash3_kernel(const uint16_t* __restrict__ qrb,
                                                     const uint16_t* __restrict__ krb,
                                                     const uint16_t* __restrict__ VhT,
                                                     uint16_t* __restrict__ ctxlatb) {
  __shared__ __align__(16) uint16_t Ks[64 * 64];     // rows l, 64 r (128B, swizzled)
  __shared__ __align__(16) uint16_t Vs[128 * 64];    // rows kk, 64 l (128B, swizzled)
  __shared__ __align__(16) uint16_t Ps[4][16 * 64];  // per-wave P, swizzled
  int bh = blockIdx.x;
  int b = bh >> 4, h = bh & 15;
  int s0 = blockIdx.y * 64;
  int tid = threadIdx.x, wave = tid >> 6, lane = tid & 63;
  int lr = lane >> 4, lc = lane & 15;
  int rS = lane >> 3, sl = lane & 7;

  // Q fragments (A-operand): row = s0 + wave*16 + lc, k = ks*32 + lr*8
  const uint16_t* qrow = qrb + (size_t)(b * 1024 + s0 + wave * 16 + lc) * 1024 + h * 64;
  short8 qa[2];
  qa[0] = *(const short8*)(qrow + lr * 8);
  qa[1] = *(const short8*)(qrow + 32 + lr * 8);

  float m_run[4], l_run[4];
#pragma unroll
  for (int r = 0; r < 4; ++r) {
    m_run[r] = -1e30f;
    l_run[r] = 0.f;
  }
  f32x4 o[8] = {};

  const uint16_t* krbase = krb + (size_t)(b * 1024) * 1024 + h * 64;
  const uint16_t* vtbase = VhT + (size_t)(b * 2048 + h * 128) * 1024;

  for (int l0 = 0; l0 < 1024; l0 += 64) {
    __syncthreads();
#pragma unroll
    for (int i = 0; i < 2; ++i) {  // stage K tile: 8KB
      int idx = wave * 2 + i;
      int row = idx * 8 + rS;
      GLOAD16(krbase + (size_t)(l0 + row) * 1024 + ((sl ^ (row & 7)) << 3),
              (uint8_t*)Ks + idx * 1024);
    }
#pragma unroll
    for (int i = 0; i < 4; ++i) {  // stage V^T tile: 16KB
      int idx = wave * 4 + i;
      int row = idx * 8 + rS;
      GLOAD16(vtbase + (size_t)row * 1024 + l0 + ((sl ^ (row & 7)) << 3),
              (uint8_t*)Vs + idx * 1024);
    }
    __syncthreads();

    // QK^T: sc[nt] covers cols nt*16+lc, rows lr*4+r
    f32x4 sc[4];
#pragma unroll
    for (int nt = 0; nt < 4; ++nt) {
      int rowk = nt * 16 + lc;
      short8 kb0 = *(const short8*)((const uint8_t*)Ks + rowk * 128 + ((lr ^ (rowk & 7)) << 4));
      short8 kb1 =
          *(const short8*)((const uint8_t*)Ks + rowk * 128 + (((4 + lr) ^ (rowk & 7)) << 4));
      f32x4 z = {};
      z = __builtin_amdgcn_mfma_f32_16x16x32_bf16(qa[0], kb0, z, 0, 0, 0);
      sc[nt] = __builtin_amdgcn_mfma_f32_16x16x32_bf16(qa[1], kb1, z, 0, 0, 0);
    }

    // online softmax (wave-parallel, rows lr*4+r)
    float scale[4], rmax[4];
#pragma unroll
    for (int r = 0; r < 4; ++r) {
      float mx = fmaxf(fmaxf(sc[0][r], sc[1][r]), fmaxf(sc[2][r], sc[3][r]));
      mx = fmaxf(mx, __shfl_xor(mx, 1));
      mx = fmaxf(mx, __shfl_xor(mx, 2));
      mx = fmaxf(mx, __shfl_xor(mx, 4));
      mx = fmaxf(mx, __shfl_xor(mx, 8));
      float mn = fmaxf(m_run[r], mx);
      scale[r] = __expf(m_run[r] - mn);
      m_run[r] = mn;
      rmax[r] = mn;
    }
    float ps[4] = {0.f, 0.f, 0.f, 0.f};
#pragma unroll
    for (int nt = 0; nt < 4; ++nt)
#pragma unroll
      for (int r = 0; r < 4; ++r) {
        float p = __expf(sc[nt][r] - rmax[r]);
        ps[r] += p;
        int prow = lr * 4 + r;
        int pcol = nt * 16 + lc;
        uint32_t addr = prow * 128 + ((((pcol >> 3) ^ (prow & 7))) << 4) + (pcol & 7) * 2;
        *(uint16_t*)((uint8_t*)Ps[wave] + addr) = f2b(p);
      }
#pragma unroll
    for (int r = 0; r < 4; ++r) {
      float s = ps[r];
      s += __shfl_xor(s, 1);
      s += __shfl_xor(s, 2);
      s += __shfl_xor(s, 4);
      s += __shfl_xor(s, 8);
      l_run[r] = l_run[r] * scale[r] + s;
    }
#pragma unroll
    for (int nt = 0; nt < 8; ++nt)
#pragma unroll
      for (int r = 0; r < 4; ++r) o[nt][r] *= scale[r];

    // P as A-fragment (wave-local LDS bounce; compiler inserts lgkmcnt)
    short8 pa[2];
#pragma unroll
    for (int ks = 0; ks < 2; ++ks) {
      int slot = ks * 4 + lr;
      pa[ks] = *(const short8*)((const uint8_t*)Ps[wave] + lc * 128 + ((slot ^ (lc & 7)) << 4));
    }
    // PV: o[nt] covers kk cols nt*16+lc
#pragma unroll
    for (int nt = 0; nt < 8; ++nt) {
      int rowv = nt * 16 + lc;
      short8 vb0 = *(const short8*)((const uint8_t*)Vs + rowv * 128 + ((lr ^ (rowv & 7)) << 4));
      short8 vb1 =
          *(const short8*)((const uint8_t*)Vs + rowv * 128 + (((4 + lr) ^ (rowv & 7)) << 4));
      o[nt] = __builtin_amdgcn_mfma_f32_16x16x32_bf16(pa[0], vb0, o[nt], 0, 0, 0);
      o[nt] = __builtin_amdgcn_mfma_f32_16x16x32_bf16(pa[1], vb1, o[nt], 0, 0, 0);
    }
  }
  // epilogue
  uint16_t* orow = ctxlatb + (size_t)(b * 1024 + s0 + wave * 16) * 2048 + h * 128;
#pragma unroll
  for (int nt = 0; nt < 8; ++nt)
#pragma unroll
    for (int r = 0; r < 4; ++r)
      orow[(size_t)(lr * 4 + r) * 2048 + nt * 16 + lc] = f2b(o[nt][r] / l_run[r]);
}

extern "C" void kernel_launch(void* const* d_in, const int* in_sizes, int n_in,
                              void* d_out, int out_size, void* d_ws, size_t ws_size,
                              hipStream_t stream) {
  const float* hidden_q = (const float*)d_in[0];
  const float* kv_c = (const float*)d_in[1];
  const float* Wq = (const float*)d_in[2];
  const float* w_kc_q = (const float*)d_in[3];
  const float* W_qr = (const float*)d_in[4];
  const float* W_kr = (const float*)d_in[5];
  const float* w_kc_kv = (const float*)d_in[6];
  const float* Wo = (const float*)d_in[7];
  float* out = (float*)d_out;

  uint8_t* p = (uint8_t*)d_ws;
  float* cosT = (float*)p;         p += 262144;
  float* sinT = (float*)p;         p += 262144;
  uint16_t* hqb = (uint16_t*)p;    p += 8388608;  // hidden_q bf16 [2048][2048]
  uint16_t* kvb = (uint16_t*)p;    p += 2097152;  // kv_c bf16 [2048][512]
  uint16_t* wkvb = (uint16_t*)p;   p += 2097152;  // w_kc_kv bf16 [2048][512]
  uint16_t* Wob = (uint16_t*)p;    p += 8388608;  // Wo bf16 [2048][2048]
  uint16_t* WfoldT = (uint16_t*)p; p += 4194304;  // [h*64+r][2048]
  uint16_t* qrb = (uint16_t*)p;    p += 4194304;  // [2048][1024]
  uint16_t* krb = (uint16_t*)p;    p += 4194304;  // [2048][1024]
  uint16_t* VhT = (uint16_t*)p;    p += 8388608;  // [b*2048 + h*128 + kk][1024]
  uint16_t* WqT = (uint16_t*)p;    p += 8388608;  // Wq^T bf16 [d=2048][k_g=2048]
  uint16_t* WqrT = (uint16_t*)p;   p += 3145728;  // [h][64][1536]
  uint16_t* wkcqb = (uint16_t*)p;  p += 6291456;  // [h][128][1536]
  uint16_t* tmpT = (uint16_t*)p;   p += 262144;   // [h][64][128]
  uint16_t* WkrT = (uint16_t*)p;   p += 1048576;  // [h*64+r][512]
  // ctxlatb overlays WqT (WqT dead after fold2; flash3 writes ctxlatb afterwards)
  uint16_t* ctxlatb = WqT;

  convert_kernel<<<dim3(2048), dim3(256), 0, stream>>>(hidden_q, hqb);
  convert_kernel<<<dim3(512), dim3(256), 0, stream>>>(kv_c, kvb);
  convert_kernel<<<dim3(512), dim3(256), 0, stream>>>(w_kc_kv, wkvb);
  convert_kernel<<<dim3(2048), dim3(256), 0, stream>>>(Wo, Wob);
  convert_kernel<<<dim3(1536), dim3(256), 0, stream>>>(w_kc_q, wkcqb);
  rope_tables_kernel<<<dim3(1024), dim3(64), 0, stream>>>(cosT, sinT);
  // W_qr [h][1536][64] -> WqrT [h][64][1536]
  transpose_conv_kernel<<<dim3(48, 2, 16), dim3(256), 0, stream>>>((const float*)W_qr, WqrT, 1536,
                                                                   64, 98304, 98304);
  // Wq [2048][2048] -> WqT [2048][2048]
  transpose_conv_kernel<<<dim3(64, 64, 1), dim3(256), 0, stream>>>(Wq, WqT, 2048, 2048, 0, 0);
  // W_kr [h][512][64] -> WkrT [h][64][512]
  transpose_conv_kernel<<<dim3(16, 2, 16), dim3(256), 0, stream>>>((const float*)W_kr, WkrT, 512,
                                                                   64, 32768, 32768);
  // fold1: tmpT[h][r][k] = sum_q WqrT[h][r][q] * wkcqb[h][k][q]   (M=64,N=128,K=1536)
  gemm_mfma_kernel<64, 1><<<dim3(1, 1, 16), dim3(256), 0, stream>>>(
      WqrT, wkcqb, tmpT, 1536, 1536, 1536, 128, 98304, 196608, 8192);
  // fold2: WfoldT[h*64+r][d] = sum_k tmpT[h][r][k] * WqT[d][h*128+k]  (M=64,N=2048,K=128)
  gemm_mfma_kernel<64, 1><<<dim3(1, 16, 16), dim3(256), 0, stream>>>(
      tmpT, WqT, WfoldT, 128, 128, 2048, 2048, 8192, 128, 131072);
  // qr = hqb @ WfoldT^T  [2048][1024]
  gemm_mfma_kernel<128, 1><<<dim3(16, 8), dim3(256), 0, stream>>>(hqb, WfoldT, qrb, 2048, 2048,
                                                                  2048, 1024, 0, 0, 0);
  // kr = kvb @ WkrT^T    [2048][1024]
  gemm_mfma_kernel<128, 1><<<dim3(16, 8), dim3(256), 0, stream>>>(kvb, WkrT, krb, 512, 512, 512,
                                                                  1024, 0, 0, 0);
  // VhT[b*2048+h*128+kk][l] via EPI=2
  gemm_mfma_kernel<128, 2><<<dim3(16, 16), dim3(256), 0, stream>>>(kvb, wkvb, VhT, 512, 512, 512,
                                                                   0, 0, 0, 0);
  rope_bf16_kernel<<<dim3(8192), dim3(256), 0, stream>>>(qrb, cosT, sinT);
  rope_bf16_kernel<<<dim3(8192), dim3(256), 0, stream>>>(krb, cosT, sinT);
  flash3_kernel<<<dim3(32, 16), dim3(256), 0, stream>>>(qrb, krb, VhT, ctxlatb);
  // out = ctxlatb @ Wob^T  [2048][2048] f32
  gemm_mfma_kernel<128, 0><<<dim3(16, 16), dim3(256), 0, stream>>>(ctxlatb, Wob, out, 2048, 2048,
                                                                   2048, 2048, 0, 0, 0);
}

// Round 5
// 171.558 us; speedup vs baseline: 48.5887x; 1.2476x over previous
//
#include <hip/hip_runtime.h>
#include <math.h>
#include <stdint.h>

// Sizes (fixed): B=2, S=L=1024, h=16, k=128, d_c=512, d_cq=1536, r=64, dim_q=2048

typedef __attribute__((ext_vector_type(8))) short short8;
typedef __attribute__((ext_vector_type(4))) float f32x4;

#define GLOAD16(gsrc, ldst)                                                            \
  __builtin_amdgcn_global_load_lds((const __attribute__((address_space(1))) void*)(gsrc), \
                                   (__attribute__((address_space(3))) void*)(ldst), 16, 0, 0)

__device__ inline uint16_t f2b(float x) {  // round-to-nearest-even f32 -> bf16
  uint32_t u = __builtin_bit_cast(uint32_t, x);
  u += 0x7fff + ((u >> 16) & 1);
  return (uint16_t)(u >> 16);
}
__device__ inline float b2f(uint16_t b) {
  uint32_t u = ((uint32_t)b) << 16;
  return __builtin_bit_cast(float, u);
}
__device__ inline uint32_t cvtpk_bf16(float lo, float hi) {  // packs 2 f32 -> 2 bf16 (RNE)
  uint32_t d;
  asm("v_cvt_pk_bf16_f32 %0, %1, %2" : "=v"(d) : "v"(lo), "v"(hi));
  return d;
}

// ---------------- fused f32 -> bf16 convert for 5 buffers (8 el/thread) ----------------
// block counts: hq 2048 | kv 512 | wkv 512 | Wo 2048 | wkcq 1536  (total 6656)
__global__ __launch_bounds__(256) void convert5_kernel(
    const float* __restrict__ s0, uint16_t* __restrict__ t0, const float* __restrict__ s1,
    uint16_t* __restrict__ t1, const float* __restrict__ s2, uint16_t* __restrict__ t2,
    const float* __restrict__ s3, uint16_t* __restrict__ t3, const float* __restrict__ s4,
    uint16_t* __restrict__ t4) {
  int bid = blockIdx.x;
  const float* s;
  uint16_t* t;
  int off;
  if (bid < 2048) { s = s0; t = t0; off = bid; }
  else if (bid < 2560) { s = s1; t = t1; off = bid - 2048; }
  else if (bid < 3072) { s = s2; t = t2; off = bid - 2560; }
  else if (bid < 5120) { s = s3; t = t3; off = bid - 3072; }
  else { s = s4; t = t4; off = bid - 5120; }
  int i = off * 256 + threadIdx.x;
  const float4* s4v = (const float4*)s;
  float4 a = s4v[i * 2], b = s4v[i * 2 + 1];
  union {
    uint16_t u[8];
    uint4 v;
  } o;
  o.u[0] = f2b(a.x); o.u[1] = f2b(a.y); o.u[2] = f2b(a.z); o.u[3] = f2b(a.w);
  o.u[4] = f2b(b.x); o.u[5] = f2b(b.y); o.u[6] = f2b(b.z); o.u[7] = f2b(b.w);
  ((uint4*)t)[i] = o.v;
}

// ---------------- tiled transpose + convert: src f32 [R][C] -> dst bf16 [C][R] ----------------
__global__ __launch_bounds__(256) void transpose_conv_kernel(const float* __restrict__ src,
                                                             uint16_t* __restrict__ dst,
                                                             int R, int C, int sOff, int dOff) {
  __shared__ float t[32][33];
  src += (size_t)blockIdx.z * sOff;
  dst += (size_t)blockIdx.z * dOff;
  int r0 = blockIdx.x * 32, c0 = blockIdx.y * 32;
  int tr = threadIdx.x >> 5, tc = threadIdx.x & 31;
#pragma unroll
  for (int i = 0; i < 4; ++i) t[tr + i * 8][tc] = src[(size_t)(r0 + tr + i * 8) * C + c0 + tc];
  __syncthreads();
#pragma unroll
  for (int i = 0; i < 4; ++i)
    dst[(size_t)(c0 + tr + i * 8) * R + r0 + tc] = f2b(t[tc][tr + i * 8]);
}

// ---------------- rope tables: K-tables plain, Q-tables pre-scaled by log2(e) ----------------
__global__ __launch_bounds__(64) void rope_tables_kernel(float* __restrict__ cosK,
                                                         float* __restrict__ sinK,
                                                         float* __restrict__ cosQ,
                                                         float* __restrict__ sinQ) {
  const float LOG2E = 1.44269504088896341f;
  int s = blockIdx.x;
  int j = threadIdx.x;
  int i = j & 31;
  float inv = powf(10000.0f, -(float)(2 * i) / 64.0f);
  float ang = (float)s * inv;
  float c = cosf(ang), sn = sinf(ang);
  cosK[s * 64 + j] = c;
  sinK[s * 64 + j] = sn;
  cosQ[s * 64 + j] = c * LOG2E;
  sinQ[s * 64 + j] = sn * LOG2E;
}

// ---------------- MFMA GEMM: C[.., M, N] = A[z][M,K]bf16 @ Bt[z][N,K]bf16^T ----------------
// Tile BM x 128, BK=64, 256 thr (4 waves 2x2), XOR slot swizzle, global_load_lds staging.
// EPI 0: f32 row-major; 1: bf16 row-major; 2: bf16 VhT layout; 3: bf16 + fused rope (rc/rs tables)
template <int BM, int EPI>
__global__ __launch_bounds__(256) void gemm_mfma_kernel(const uint16_t* __restrict__ A,
                                                        const uint16_t* __restrict__ Bt,
                                                        void* __restrict__ Cv, int K, int lda,
                                                        int ldb, int ldc, int aZ, int bZ, int cZ,
                                                        const float* __restrict__ rc,
                                                        const float* __restrict__ rs) {
  constexpr int MT = BM / 32;  // m-fragments per wave (2 or 4)
  __shared__ __align__(16) uint16_t As[BM * 64];
  __shared__ __align__(16) uint16_t Bs[128 * 64];
  int z = blockIdx.z;
  A += (size_t)z * aZ;
  Bt += (size_t)z * bZ;
  int m0 = blockIdx.x * BM, n0 = blockIdx.y * 128;
  int tid = threadIdx.x;
  int wave = tid >> 6, lane = tid & 63;
  int wm = wave >> 1, wn = wave & 1;
  int rS = lane >> 3, sl = lane & 7;
  int lr = lane >> 4, lc = lane & 15;
  f32x4 acc[MT][4] = {};
  for (int k0 = 0; k0 < K; k0 += 64) {
    __syncthreads();
#pragma unroll
    for (int i = 0; i < MT; ++i) {
      int idx = wave * MT + i;
      int row = idx * 8 + rS;
      GLOAD16(A + (size_t)(m0 + row) * lda + k0 + ((sl ^ (row & 7)) << 3),
              (uint8_t*)As + idx * 1024);
    }
#pragma unroll
    for (int i = 0; i < 4; ++i) {
      int idx = wave * 4 + i;
      int row = idx * 8 + rS;
      GLOAD16(Bt + (size_t)(n0 + row) * ldb + k0 + ((sl ^ (row & 7)) << 3),
              (uint8_t*)Bs + idx * 1024);
    }
    __syncthreads();
    short8 af[MT][2], bf[4][2];
#pragma unroll
    for (int t = 0; t < MT; ++t)
#pragma unroll
      for (int ks = 0; ks < 2; ++ks) {
        int slot = ks * 4 + lr;
        int ra = wm * (BM / 2) + t * 16 + lc;
        af[t][ks] = *(const short8*)((const uint8_t*)As + ra * 128 + ((slot ^ (ra & 7)) << 4));
      }
#pragma unroll
    for (int t = 0; t < 4; ++t)
#pragma unroll
      for (int ks = 0; ks < 2; ++ks) {
        int slot = ks * 4 + lr;
        int rb = wn * 64 + t * 16 + lc;
        bf[t][ks] = *(const short8*)((const uint8_t*)Bs + rb * 128 + ((slot ^ (rb & 7)) << 4));
      }
    __builtin_amdgcn_s_setprio(1);
#pragma unroll
    for (int mt = 0; mt < MT; ++mt)
#pragma unroll
      for (int nt = 0; nt < 4; ++nt) {
        acc[mt][nt] =
            __builtin_amdgcn_mfma_f32_16x16x32_bf16(af[mt][0], bf[nt][0], acc[mt][nt], 0, 0, 0);
        acc[mt][nt] =
            __builtin_amdgcn_mfma_f32_16x16x32_bf16(af[mt][1], bf[nt][1], acc[mt][nt], 0, 0, 0);
      }
    __builtin_amdgcn_s_setprio(0);
  }
  if (EPI == 3) {
#pragma unroll
    for (int mt = 0; mt < MT; ++mt)
#pragma unroll
      for (int nt = 0; nt < 4; ++nt)
#pragma unroll
        for (int r = 0; r < 4; ++r) {
          int m = m0 + wm * (BM / 2) + mt * 16 + lr * 4 + r;
          int n = n0 + wn * 64 + nt * 16 + lc;
          int pos = m & 1023, j = n & 63;
          float x = acc[mt][nt][r];
          float prt = acc[mt][nt ^ 2][r];
          float rot = (nt & 2) ? prt : -prt;
          float v = fmaf(x, rc[pos * 64 + j], rot * rs[pos * 64 + j]);
          ((uint16_t*)Cv)[(size_t)m * ldc + n] = f2b(v);
        }
  } else {
#pragma unroll
    for (int mt = 0; mt < MT; ++mt)
#pragma unroll
      for (int nt = 0; nt < 4; ++nt)
#pragma unroll
        for (int r = 0; r < 4; ++r) {
          int m = m0 + wm * (BM / 2) + mt * 16 + lr * 4 + r;
          int n = n0 + wn * 64 + nt * 16 + lc;
          float v = acc[mt][nt][r];
          if (EPI == 0)
            ((float*)Cv)[(size_t)z * cZ + (size_t)m * ldc + n] = v;
          else if (EPI == 1)
            ((uint16_t*)Cv)[(size_t)z * cZ + (size_t)m * ldc + n] = f2b(v);
          else
            ((uint16_t*)Cv)[((size_t)((m >> 10) * 2048 + n)) * 1024 + (m & 1023)] = f2b(v);
        }
  }
}

// ---------------- MFMA flash attention (exp2 domain; q pre-scaled by log2e) ----------------
// grid (bh=32, stile=16), 256 thr = 4 waves; wave owns 16 q-rows. Out: ctxlatb bf16 [b*1024+s][2048]
__global__ __launch_bounds__(256) void flash3_kernel(const uint16_t* __restrict__ qrb,
                                                     const uint16_t* __restrict__ krb,
                                                     const uint16_t* __restrict__ VhT,
                                                     uint16_t* __restrict__ ctxlatb) {
  __shared__ __align__(16) uint16_t Ks[64 * 64];     // rows l, 64 r (128B, swizzled)
  __shared__ __align__(16) uint16_t Vs[128 * 64];    // rows kk, 64 l (128B, swizzled)
  __shared__ __align__(16) uint16_t Ps[4][16 * 64];  // per-wave P, swizzled
  int bh = blockIdx.x;
  int b = bh >> 4, h = bh & 15;
  int s0 = blockIdx.y * 64;
  int tid = threadIdx.x, wave = tid >> 6, lane = tid & 63;
  int lr = lane >> 4, lc = lane & 15;
  int rS = lane >> 3, sl = lane & 7;

  const uint16_t* qrow = qrb + (size_t)(b * 1024 + s0 + wave * 16 + lc) * 1024 + h * 64;
  short8 qa[2];
  qa[0] = *(const short8*)(qrow + lr * 8);
  qa[1] = *(const short8*)(qrow + 32 + lr * 8);

  float m_run[4], l_run[4];
#pragma unroll
  for (int r = 0; r < 4; ++r) {
    m_run[r] = -1e30f;
    l_run[r] = 0.f;
  }
  f32x4 o[8] = {};

  const uint16_t* krbase = krb + (size_t)(b * 1024) * 1024 + h * 64;
  const uint16_t* vtbase = VhT + (size_t)(b * 2048 + h * 128) * 1024;

  for (int l0 = 0; l0 < 1024; l0 += 64) {
    __syncthreads();
#pragma unroll
    for (int i = 0; i < 2; ++i) {  // stage K tile: 8KB
      int idx = wave * 2 + i;
      int row = idx * 8 + rS;
      GLOAD16(krbase + (size_t)(l0 + row) * 1024 + ((sl ^ (row & 7)) << 3),
              (uint8_t*)Ks + idx * 1024);
    }
#pragma unroll
    for (int i = 0; i < 4; ++i) {  // stage V^T tile: 16KB
      int idx = wave * 4 + i;
      int row = idx * 8 + rS;
      GLOAD16(vtbase + (size_t)row * 1024 + l0 + ((sl ^ (row & 7)) << 3),
              (uint8_t*)Vs + idx * 1024);
    }
    __syncthreads();

    // QK^T: sc[nt] covers cols nt*16+lc, rows lr*4+r   (scores already in log2 domain)
    f32x4 sc[4];
    __builtin_amdgcn_s_setprio(1);
#pragma unroll
    for (int nt = 0; nt < 4; ++nt) {
      int rowk = nt * 16 + lc;
      short8 kb0 = *(const short8*)((const uint8_t*)Ks + rowk * 128 + ((lr ^ (rowk & 7)) << 4));
      short8 kb1 =
          *(const short8*)((const uint8_t*)Ks + rowk * 128 + (((4 + lr) ^ (rowk & 7)) << 4));
      f32x4 z = {};
      z = __builtin_amdgcn_mfma_f32_16x16x32_bf16(qa[0], kb0, z, 0, 0, 0);
      sc[nt] = __builtin_amdgcn_mfma_f32_16x16x32_bf16(qa[1], kb1, z, 0, 0, 0);
    }
    __builtin_amdgcn_s_setprio(0);

    // per-row tile max (16-lane reduce)
    float mx[4];
#pragma unroll
    for (int r = 0; r < 4; ++r) {
      float m = fmaxf(fmaxf(sc[0][r], sc[1][r]), fmaxf(sc[2][r], sc[3][r]));
      m = fmaxf(m, __shfl_xor(m, 1));
      m = fmaxf(m, __shfl_xor(m, 2));
      m = fmaxf(m, __shfl_xor(m, 4));
      mx[r] = fmaxf(m, __shfl_xor(m, 8));
    }
    // defer-max: skip rescale when all rows grew <= 8 (log2 domain -> P <= 256)
    bool grow = false;
#pragma unroll
    for (int r = 0; r < 4; ++r) grow |= (mx[r] > m_run[r] + 8.0f);
    bool upd = (__ballot(grow) != 0ULL);  // wave-uniform
    float scale[4];
    if (upd) {
#pragma unroll
      for (int r = 0; r < 4; ++r) {
        float mn = fmaxf(m_run[r], mx[r]);
        scale[r] = exp2f(m_run[r] - mn);
        m_run[r] = mn;
      }
    }
    float ps[4] = {0.f, 0.f, 0.f, 0.f};
#pragma unroll
    for (int nt = 0; nt < 4; ++nt) {
      int pcol = nt * 16 + lc;
#pragma unroll
      for (int rp = 0; rp < 2; ++rp) {
        float p0 = exp2f(sc[nt][rp * 2] - m_run[rp * 2]);
        float p1 = exp2f(sc[nt][rp * 2 + 1] - m_run[rp * 2 + 1]);
        ps[rp * 2] += p0;
        ps[rp * 2 + 1] += p1;
        uint32_t u = cvtpk_bf16(p0, p1);
        int prow0 = lr * 4 + rp * 2;
        uint32_t a0 = prow0 * 128 + ((((pcol >> 3) ^ (prow0 & 7))) << 4) + (pcol & 7) * 2;
        int prow1 = prow0 + 1;
        uint32_t a1 = prow1 * 128 + ((((pcol >> 3) ^ (prow1 & 7))) << 4) + (pcol & 7) * 2;
        *(uint16_t*)((uint8_t*)Ps[wave] + a0) = (uint16_t)u;
        *(uint16_t*)((uint8_t*)Ps[wave] + a1) = (uint16_t)(u >> 16);
      }
    }
#pragma unroll
    for (int r = 0; r < 4; ++r) {
      float s = ps[r];
      s += __shfl_xor(s, 1);
      s += __shfl_xor(s, 2);
      s += __shfl_xor(s, 4);
      s += __shfl_xor(s, 8);
      ps[r] = s;
    }
    if (upd) {
#pragma unroll
      for (int r = 0; r < 4; ++r) l_run[r] = l_run[r] * scale[r] + ps[r];
#pragma unroll
      for (int nt = 0; nt < 8; ++nt)
#pragma unroll
        for (int r = 0; r < 4; ++r) o[nt][r] *= scale[r];
    } else {
#pragma unroll
      for (int r = 0; r < 4; ++r) l_run[r] += ps[r];
    }

    // P as A-fragment (wave-local LDS bounce; compiler inserts lgkmcnt)
    short8 pa[2];
#pragma unroll
    for (int ks = 0; ks < 2; ++ks) {
      int slot = ks * 4 + lr;
      pa[ks] = *(const short8*)((const uint8_t*)Ps[wave] + lc * 128 + ((slot ^ (lc & 7)) << 4));
    }
    // PV: o[nt] covers kk cols nt*16+lc
    __builtin_amdgcn_s_setprio(1);
#pragma unroll
    for (int nt = 0; nt < 8; ++nt) {
      int rowv = nt * 16 + lc;
      short8 vb0 = *(const short8*)((const uint8_t*)Vs + rowv * 128 + ((lr ^ (rowv & 7)) << 4));
      short8 vb1 =
          *(const short8*)((const uint8_t*)Vs + rowv * 128 + (((4 + lr) ^ (rowv & 7)) << 4));
      o[nt] = __builtin_amdgcn_mfma_f32_16x16x32_bf16(pa[0], vb0, o[nt], 0, 0, 0);
      o[nt] = __builtin_amdgcn_mfma_f32_16x16x32_bf16(pa[1], vb1, o[nt], 0, 0, 0);
    }
    __builtin_amdgcn_s_setprio(0);
  }
  // epilogue
  uint16_t* orow = ctxlatb + (size_t)(b * 1024 + s0 + wave * 16) * 2048 + h * 128;
#pragma unroll
  for (int nt = 0; nt < 8; ++nt)
#pragma unroll
    for (int r = 0; r < 4; ++r)
      orow[(size_t)(lr * 4 + r) * 2048 + nt * 16 + lc] = f2b(o[nt][r] / l_run[r]);
}

extern "C" void kernel_launch(void* const* d_in, const int* in_sizes, int n_in,
                              void* d_out, int out_size, void* d_ws, size_t ws_size,
                              hipStream_t stream) {
  const float* hidden_q = (const float*)d_in[0];
  const float* kv_c = (const float*)d_in[1];
  const float* Wq = (const float*)d_in[2];
  const float* w_kc_q = (const float*)d_in[3];
  const float* W_qr = (const float*)d_in[4];
  const float* W_kr = (const float*)d_in[5];
  const float* w_kc_kv = (const float*)d_in[6];
  const float* Wo = (const float*)d_in[7];
  float* out = (float*)d_out;

  uint8_t* p = (uint8_t*)d_ws;
  float* cosK = (float*)p;         p += 262144;
  float* sinK = (float*)p;         p += 262144;
  float* cosQ = (float*)p;         p += 262144;
  float* sinQ = (float*)p;         p += 262144;
  uint16_t* hqb = (uint16_t*)p;    p += 8388608;  // hidden_q bf16 [2048][2048]
  uint16_t* kvb = (uint16_t*)p;    p += 2097152;  // kv_c bf16 [2048][512]
  uint16_t* wkvb = (uint16_t*)p;   p += 2097152;  // w_kc_kv bf16 [2048][512]
  uint16_t* Wob = (uint16_t*)p;    p += 8388608;  // Wo bf16 [2048][2048]
  uint16_t* WfoldT = (uint16_t*)p; p += 4194304;  // [h*64+r][2048]
  uint16_t* qrb = (uint16_t*)p;    p += 4194304;  // [2048][1024] (pre-scaled by log2e)
  uint16_t* krb = (uint16_t*)p;    p += 4194304;  // [2048][1024]
  uint16_t* VhT = (uint16_t*)p;    p += 8388608;  // [b*2048 + h*128 + kk][1024]
  uint16_t* WqT = (uint16_t*)p;    p += 8388608;  // Wq^T bf16 [d=2048][k_g=2048]
  uint16_t* WqrT = (uint16_t*)p;   p += 3145728;  // [h][64][1536]
  uint16_t* wkcqb = (uint16_t*)p;  p += 6291456;  // [h][128][1536]
  uint16_t* tmpT = (uint16_t*)p;   p += 262144;   // [h][64][128]
  uint16_t* WkrT = (uint16_t*)p;   p += 1048576;  // [h*64+r][512]
  // ctxlatb overlays WqT (WqT dead after fold2; flash3 writes ctxlatb afterwards)
  uint16_t* ctxlatb = WqT;

  convert5_kernel<<<dim3(6656), dim3(256), 0, stream>>>(hidden_q, hqb, kv_c, kvb, w_kc_kv, wkvb,
                                                        Wo, Wob, w_kc_q, wkcqb);
  rope_tables_kernel<<<dim3(1024), dim3(64), 0, stream>>>(cosK, sinK, cosQ, sinQ);
  // W_qr [h][1536][64] -> WqrT [h][64][1536]
  transpose_conv_kernel<<<dim3(48, 2, 16), dim3(256), 0, stream>>>((const float*)W_qr, WqrT, 1536,
                                                                   64, 98304, 98304);
  // Wq [2048][2048] -> WqT [2048][2048]
  transpose_conv_kernel<<<dim3(64, 64, 1), dim3(256), 0, stream>>>(Wq, WqT, 2048, 2048, 0, 0);
  // W_kr [h][512][64] -> WkrT [h][64][512]
  transpose_conv_kernel<<<dim3(16, 2, 16), dim3(256), 0, stream>>>((const float*)W_kr, WkrT, 512,
                                                                   64, 32768, 32768);
  // fold1: tmpT[h][r][k] = sum_q WqrT[h][r][q] * wkcqb[h][k][q]   (M=64,N=128,K=1536)
  gemm_mfma_kernel<64, 1><<<dim3(1, 1, 16), dim3(256), 0, stream>>>(
      WqrT, wkcqb, tmpT, 1536, 1536, 1536, 128, 98304, 196608, 8192, nullptr, nullptr);
  // fold2: WfoldT[h*64+r][d] = sum_k tmpT[h][r][k] * WqT[d][h*128+k]  (M=64,N=2048,K=128)
  gemm_mfma_kernel<64, 1><<<dim3(1, 16, 16), dim3(256), 0, stream>>>(
      tmpT, WqT, WfoldT, 128, 128, 2048, 2048, 8192, 128, 131072, nullptr, nullptr);
  // qr = rope_q(hqb @ WfoldT^T) [2048][1024], fused rope with log2e-scaled tables
  gemm_mfma_kernel<64, 3><<<dim3(32, 8), dim3(256), 0, stream>>>(hqb, WfoldT, qrb, 2048, 2048,
                                                                 2048, 1024, 0, 0, 0, cosQ, sinQ);
  // kr = rope_k(kvb @ WkrT^T) [2048][1024]
  gemm_mfma_kernel<64, 3><<<dim3(32, 8), dim3(256), 0, stream>>>(kvb, WkrT, krb, 512, 512, 512,
                                                                 1024, 0, 0, 0, cosK, sinK);
  // VhT[b*2048+h*128+kk][l] via EPI=2
  gemm_mfma_kernel<64, 2><<<dim3(32, 16), dim3(256), 0, stream>>>(kvb, wkvb, VhT, 512, 512, 512, 0,
                                                                  0, 0, 0, nullptr, nullptr);
  flash3_kernel<<<dim3(32, 16), dim3(256), 0, stream>>>(qrb, krb, VhT, ctxlatb);
  // out = ctxlatb @ Wob^T  [2048][2048] f32
  gemm_mfma_kernel<64, 0><<<dim3(32, 16), dim3(256), 0, stream>>>(ctxlatb, Wob, out, 2048, 2048,
                                                                  2048, 2048, 0, 0, 0, nullptr,
                                                                  nullptr);
}